// Round 8
// baseline (1107.973 us; speedup 1.0000x reference)
//
#include <hip/hip_runtime.h>
#include <hip/hip_bf16.h>
#include <math.h>

typedef __bf16 bf16;
typedef __attribute__((ext_vector_type(8))) __bf16 bf16x8;
typedef __attribute__((ext_vector_type(4))) float floatx4;

static_assert(sizeof(bf16x8) == 16, "bf16x8 must be 16B");

// async global->LDS, 16B per lane. LDS dest is wave-uniform base + lane*16
// (HW rule, learn_hip m104); global src is per-lane.
__device__ __forceinline__ void gld16(bf16* lds, const bf16* g) {
  __builtin_amdgcn_global_load_lds((const __attribute__((address_space(1))) void*)g,
                                   (__attribute__((address_space(3))) void*)lds, 16, 0, 0);
}

// counted-vmcnt barrier primitives (T3/T4): raw s_barrier WITHOUT the
// compiler's vmcnt(0) drain; counted wait keeps next tiles' loads in flight.
#define VMCNT(N) asm volatile("s_waitcnt vmcnt(" #N ")" ::: "memory")
#define RAW_BARRIER() asm volatile("s_barrier" ::: "memory")

// ---------------------------------------------------------------------------
// Row-normalize stru_feats (8192x512 fp32) -> bf16 unit rows
// ---------------------------------------------------------------------------
__global__ void row_normalize_kernel(const float* __restrict__ x, bf16* __restrict__ out) {
  __shared__ float red[256];
  int row = blockIdx.x;
  int t = threadIdx.x;
  float v0 = x[(size_t)row * 512 + t];
  float v1 = x[(size_t)row * 512 + t + 256];
  red[t] = v0 * v0 + v1 * v1;
  __syncthreads();
  for (int d = 128; d > 0; d >>= 1) {
    if (t < d) red[t] += red[t + d];
    __syncthreads();
  }
  float scale = 1.0f / (sqrtf(red[0]) + 1e-12f);
  out[(size_t)row * 512 + t] = (bf16)(v0 * scale);
  out[(size_t)row * 512 + t + 256] = (bf16)(v1 * scale);
}

// ---------------------------------------------------------------------------
// Elementwise fp32 -> bf16 cast (vectorized, grid-stride)
// ---------------------------------------------------------------------------
__global__ void cast_bf16_kernel(const float* __restrict__ x, bf16* __restrict__ out, long n) {
  long i = ((long)blockIdx.x * blockDim.x + threadIdx.x) * 8;
  long stride = (long)gridDim.x * blockDim.x * 8;
  for (; i < n; i += stride) {
    floatx4 a = *(const floatx4*)(x + i);
    floatx4 b = *(const floatx4*)(x + i + 4);
    bf16x8 v;
#pragma unroll
    for (int e = 0; e < 4; ++e) v[e] = (bf16)a[e];
#pragma unroll
    for (int e = 0; e < 4; ++e) v[e + 4] = (bf16)b[e];
    *(bf16x8*)(out + i) = v;
  }
}

// ---------------------------------------------------------------------------
// W [K][512] fp32 -> Wt [512][K] bf16, LDS-tiled so both sides are coalesced
// ---------------------------------------------------------------------------
__global__ void transpose_cast_kernel(const float* __restrict__ W, bf16* __restrict__ Wt, int K) {
  __shared__ float t[64][65];
  int k0 = blockIdx.x * 64;
  int n0 = blockIdx.y * 64;
#pragma unroll
  for (int m = 0; m < 16; ++m) {
    int kk = (threadIdx.x >> 6) + m * 4;
    int nn = threadIdx.x & 63;
    t[kk][nn] = W[(size_t)(k0 + kk) * 512 + n0 + nn];
  }
  __syncthreads();
#pragma unroll
  for (int m = 0; m < 16; ++m) {
    int nn = (threadIdx.x >> 6) + m * 4;
    int kk = threadIdx.x & 63;
    Wt[(size_t)(n0 + nn) * K + k0 + kk] = (bf16)t[kk][nn];
  }
}

// ---------------------------------------------------------------------------
// BN column stats over 8192 rows of H2 [8192][512]
// ---------------------------------------------------------------------------
__global__ void bn_stats_kernel(const float* __restrict__ h, float* __restrict__ colsum,
                                float* __restrict__ colsumsq) {
  int col = threadIdx.x;  // 512 threads
  int r0 = blockIdx.x * 32;
  float s = 0.f, s2 = 0.f;
  for (int r = r0; r < r0 + 32; ++r) {
    float v = h[(size_t)r * 512 + col];
    s += v;
    s2 += v * v;
  }
  atomicAdd(&colsum[col], s);
  atomicAdd(&colsumsq[col], s2);
}

// ---------------------------------------------------------------------------
// BN apply + write mm (fp32, to d_out) + row-normalized bf16 copy mmn
// ---------------------------------------------------------------------------
__global__ void bn_apply_kernel(const float* __restrict__ h, const float* __restrict__ colsum,
                                const float* __restrict__ colsumsq, const float* __restrict__ gamma,
                                const float* __restrict__ beta, float* __restrict__ mm_out,
                                bf16* __restrict__ mmn) {
  __shared__ float red[512];
  int row = blockIdx.x, col = threadIdx.x;  // 512 threads
  float mean = colsum[col] * (1.0f / 8192.0f);
  float var = colsumsq[col] * (1.0f / 8192.0f) - mean * mean;
  float inv = rsqrtf(var + 1e-5f);
  float y = (h[(size_t)row * 512 + col] - mean) * inv * gamma[col] + beta[col];
  mm_out[(size_t)row * 512 + col] = y;
  red[col] = y * y;
  __syncthreads();
  for (int d = 256; d > 0; d >>= 1) {
    if (col < d) red[col] += red[col + d];
    __syncthreads();
  }
  float scale = 1.0f / (sqrtf(red[0]) + 1e-12f);
  mmn[(size_t)row * 512 + col] = (bf16)(y * scale);
}

// ---------------------------------------------------------------------------
// MLP GEMM-NT via depth-2 global_load_lds pipeline: C = A[M][K] * B[N][K]^T.
// Block 128 rows x 64 cols; 4 waves, each wave 32 rows (2 groups) x 64 cols.
// 3 LDS buffers. Phase s: vmcnt(6) [tile s's 6 loads done, tile s+1's stay
// in flight -> never drain to 0], raw s_barrier, THEN issue tile s+2 (safe:
// buffer s-1 free after barrier) -> MFMA tile s. Swizzle via pre-swizzled
// global source chunk (LDS dest linear, m173): LDS[r][c] = global chunk
// c ^ (r&7).
// MODE 0: +bias, leaky-relu, store bf16      (MLP layer 1)
// MODE 1: +bias, store fp32                  (MLP layer 2)
// AF32 fallback (ws too small for pre-cast): simple 2-barrier staging.
// ---------------------------------------------------------------------------
template <int MODE, bool AF32>
__launch_bounds__(256, 2) __global__
void gemm_nt_kernel(const void* __restrict__ Av, const bf16* __restrict__ B,
                    const float* __restrict__ bias, bf16* __restrict__ out_bf,
                    float* __restrict__ out_f, int K) {
  __shared__ __align__(16) bf16 As[3][128][64];
  __shared__ __align__(16) bf16 Bs[3][64][64];

  const int tid = threadIdx.x;
  const int lane = tid & 63;
  const int wave = tid >> 6;
  const int q = lane >> 4;
  const int ml = lane & 15;
  const int row0 = blockIdx.x * 128;
  const int col0 = blockIdx.y * 64;

  const float* Af = (const float*)Av;
  const bf16* Ab = (const bf16*)Av;

  floatx4 acc[2][4];
#pragma unroll
  for (int g = 0; g < 2; ++g)
#pragma unroll
    for (int f = 0; f < 4; ++f) acc[g][f] = (floatx4)0.0f;

  const int nsteps = K >> 6;

  if constexpr (!AF32) {
    // gld geometry: lane covers row-in-group (lane>>3), chunk (lane&7);
    // pre-swizzled global chunk = (lane&7) ^ (lane>>3)
    const int grow = lane >> 3;
    const int gch = (lane & 7) ^ grow;

    auto stageAB = [&](int s, int b) {
      const int kt = s << 6;
#pragma unroll
      for (int m = 0; m < 4; ++m) {
        const int rb = m * 32 + wave * 8;  // rb % 8 == 0
        gld16(&As[b][rb][0], Ab + (size_t)(row0 + rb + grow) * K + kt + gch * 8);
      }
#pragma unroll
      for (int m = 0; m < 2; ++m) {
        const int rb = m * 32 + wave * 8;
        gld16(&Bs[b][rb][0], B + (size_t)(col0 + rb + grow) * K + kt + gch * 8);
      }
    };

    stageAB(0, 0);
    stageAB(1, 1);
    int cur = 0;
    for (int s = 0; s < nsteps; ++s) {
      // wait tile s's 6 loads (tile s+1's 6 remain in flight); never vmcnt(0)
      // in the steady state.
      if (s == nsteps - 1) { VMCNT(0); } else { VMCNT(6); }
      __builtin_amdgcn_sched_barrier(0);
      RAW_BARRIER();
      __builtin_amdgcn_sched_barrier(0);
      int nb = cur + 2;
      if (nb >= 3) nb -= 3;
      if (s + 2 < nsteps) stageAB(s + 2, nb);  // buffer of tile s-1: free now
      __builtin_amdgcn_s_setprio(1);
#pragma unroll
      for (int kh = 0; kh < 2; ++kh) {
        const int slot = ((q + kh * 4) ^ (ml & 7)) * 8;
        bf16x8 a0 = *(const bf16x8*)&As[cur][wave * 32 + ml][slot];
        bf16x8 a1 = *(const bf16x8*)&As[cur][wave * 32 + 16 + ml][slot];
#pragma unroll
        for (int f = 0; f < 4; ++f) {
          bf16x8 bb = *(const bf16x8*)&Bs[cur][f * 16 + ml][slot];
          acc[0][f] = __builtin_amdgcn_mfma_f32_16x16x32_bf16(a0, bb, acc[0][f], 0, 0, 0);
          acc[1][f] = __builtin_amdgcn_mfma_f32_16x16x32_bf16(a1, bb, acc[1][f], 0, 0, 0);
        }
      }
      __builtin_amdgcn_s_setprio(0);
      cur = cur + 1;
      if (cur >= 3) cur -= 3;
    }
  } else {
    // fallback: fp32 A, cvt in regs, single buffer, 2 barriers/step
    const int sr = tid >> 3;
    const int sc = tid & 7;
    for (int s = 0; s < nsteps; ++s) {
      const int kt = s << 6;
      __syncthreads();
#pragma unroll
      for (int m = 0; m < 4; ++m) {
        int r = sr + m * 32;
        const float* pp = Af + (size_t)(row0 + r) * K + kt + sc * 8;
        bf16x8 v;
#pragma unroll
        for (int e = 0; e < 8; ++e) v[e] = (bf16)pp[e];
        *(bf16x8*)&As[0][r][(sc ^ (r & 7)) * 8] = v;
      }
#pragma unroll
      for (int m = 0; m < 2; ++m) {
        int r = sr + m * 32;
        *(bf16x8*)&Bs[0][r][(sc ^ (r & 7)) * 8] =
            *(const bf16x8*)(B + (size_t)(col0 + r) * K + kt + sc * 8);
      }
      __syncthreads();
#pragma unroll
      for (int kh = 0; kh < 2; ++kh) {
        const int slot = ((q + kh * 4) ^ (ml & 7)) * 8;
        bf16x8 a0 = *(const bf16x8*)&As[0][wave * 32 + ml][slot];
        bf16x8 a1 = *(const bf16x8*)&As[0][wave * 32 + 16 + ml][slot];
#pragma unroll
        for (int f = 0; f < 4; ++f) {
          bf16x8 bb = *(const bf16x8*)&Bs[0][f * 16 + ml][slot];
          acc[0][f] = __builtin_amdgcn_mfma_f32_16x16x32_bf16(a0, bb, acc[0][f], 0, 0, 0);
          acc[1][f] = __builtin_amdgcn_mfma_f32_16x16x32_bf16(a1, bb, acc[1][f], 0, 0, 0);
        }
      }
    }
  }

#pragma unroll
  for (int f = 0; f < 4; ++f) {
    int colg = col0 + f * 16 + ml;
    float bv = bias[colg];
#pragma unroll
    for (int g = 0; g < 2; ++g)
#pragma unroll
      for (int i = 0; i < 4; ++i) {
        int rowg = row0 + wave * 32 + g * 16 + q * 4 + i;
        float v = acc[g][f][i] + bv;
        if constexpr (MODE == 0) {
          v = v >= 0.f ? v : 0.01f * v;
          out_bf[(size_t)rowg * 512 + colg] = (bf16)v;
        } else {
          out_f[(size_t)rowg * 512 + colg] = v;
        }
      }
  }
}

// ---------------------------------------------------------------------------
// FUSED top-k / softmax-sum GEMM-NT, depth-2 global_load_lds pipeline.
// Computes BOTH  mmn @ mmn^T (neighbor top-6)  and  strun @ mmn^T (sm top-6 +
// rowsum(exp(2c)))  in one pass over the shared B tile (mmn).
// R8 fixes: (1) amdgpu_waves_per_eu(2,2) -> 256-VGPR budget matching the
// LDS-limited 2 blocks/CU, so afr[2][16] (128 VGPR) can actually be resident
// (R7 VGPR_Count=124 proved the compiler sank the A loads into the ct loop);
// (2) keep-alive "+v" asm pins afr in registers (blocks rematerialization);
// (3) max-of-4 gate skips the pack+compare epilogue for no-insert tiles.
// Top-6 per-lane as packed keys: (monotonic_bits(v) & ~0x1FFF) | (8191-col).
// ---------------------------------------------------------------------------
__device__ __forceinline__ unsigned pack_val(float v) {
  unsigned u = __float_as_uint(v);
  u = (u & 0x80000000u) ? ~u : (u | 0x80000000u);
  return u & 0xFFFFE000u;
}
__device__ __forceinline__ unsigned pack_key(float v, int col) {
  return pack_val(v) | (unsigned)(8191 - col);
}

#define NPARTS 8

__attribute__((amdgpu_waves_per_eu(2, 2))) __launch_bounds__(256) __global__
void topk_sm_fused_kernel(const bf16* __restrict__ Amm, const bf16* __restrict__ Ast,
                          const bf16* __restrict__ B, unsigned* __restrict__ keys_mm,
                          unsigned* __restrict__ keys_sm, float* __restrict__ rowsum_part) {
  __shared__ __align__(16) bf16 Bs[3][64][128];

  const int tid = threadIdx.x;
  const int lane = tid & 63;
  const int wave = tid >> 6;
  const int q = lane >> 4;
  const int ml = lane & 15;
  const int row0 = blockIdx.x * 64;
  const int part = blockIdx.y;

  // gld geometry: lane covers row-in-group (lane>>4), chunk (lane&15);
  // row&15 for this lane = wave*4 + (lane>>4); pre-swizzled global chunk:
  const int strw = wave * 4 + (lane >> 4);
  const int gch = (lane & 15) ^ strw;

  // A fragments resident in registers: g=0 -> mmn rows, g=1 -> strun rows
  bf16x8 afr[2][16];
#pragma unroll
  for (int g = 0; g < 2; ++g) {
    const bf16* ap = (g == 0 ? Amm : Ast) + (size_t)(row0 + wave * 16 + ml) * 512 + q * 8;
#pragma unroll
    for (int s = 0; s < 16; ++s) afr[g][s] = *(const bf16x8*)(ap + s * 32);
  }
  // pin afr in VGPRs: in-out asm redefines each value in a register, making
  // remat-from-memory illegal (R7's compiler sank these loads into the loop).
#pragma unroll
  for (int g = 0; g < 2; ++g)
#pragma unroll
    for (int s = 0; s < 16; ++s) asm volatile("" : "+v"(afr[g][s]));

  // per-lane packed top-6 for the 4 rows (q*4+i) of each A-set
  unsigned p6[2][4][6];
#pragma unroll
  for (int g = 0; g < 2; ++g)
#pragma unroll
    for (int i = 0; i < 4; ++i)
#pragma unroll
      for (int j = 0; j < 6; ++j) p6[g][i][j] = 0u;
  float srow[4] = {0.f, 0.f, 0.f, 0.f};

  // stage tile u (u = ct*4 + ktile) into buffer b, async, zero registers
  auto stage = [&](int u, int b) {
    const bf16* bp =
        B + (size_t)(part * 1024 + (u >> 2) * 64 + strw) * 512 + (u & 3) * 128 + gch * 8;
#pragma unroll
    for (int m = 0; m < 4; ++m)
      gld16(&Bs[b][wave * 4 + m * 16][0], bp + (size_t)m * 16 * 512);
  };

  // prologue: issue tiles 0 and 1
  stage(0, 0);
  stage(1, 1);
  int cur = 0;

  for (int ct = 0; ct < 16; ++ct) {
    const int col0 = part * 1024 + ct * 64;
    floatx4 acc[2][4];
#pragma unroll
    for (int g = 0; g < 2; ++g)
#pragma unroll
      for (int f = 0; f < 4; ++f) acc[g][f] = (floatx4)0.0f;

#pragma unroll
    for (int kt4 = 0; kt4 < 4; ++kt4) {
      const int t = ct * 4 + kt4;
      // wait my tile-t loads (4); leave tile t+1's 4 in flight. Only the very
      // last phase drains to 0.
      if (kt4 == 3) {
        if (ct == 15) { VMCNT(0); } else { VMCNT(4); }
      } else {
        VMCNT(4);
      }
      __builtin_amdgcn_sched_barrier(0);
      RAW_BARRIER();
      __builtin_amdgcn_sched_barrier(0);
      // issue tile t+2 into the buffer tile t-1 used (free: all waves passed
      // the barrier, so their phase t-1 reads are issued). ~2 phases of cover.
      {
        int nb = cur + 2;
        if (nb >= 3) nb -= 3;
        if (ct < 15 || kt4 < 2) stage(t + 2, nb);
      }
      __builtin_amdgcn_s_setprio(1);
#pragma unroll
      for (int kk2 = 0; kk2 < 4; ++kk2) {
        const int sc2 = (kk2 * 4 + q) ^ ml;
#pragma unroll
        for (int f = 0; f < 4; ++f) {
          bf16x8 b = *(const bf16x8*)&Bs[cur][f * 16 + ml][sc2 * 8];
          acc[0][f] = __builtin_amdgcn_mfma_f32_16x16x32_bf16(afr[0][kt4 * 4 + kk2], b, acc[0][f], 0, 0, 0);
          acc[1][f] = __builtin_amdgcn_mfma_f32_16x16x32_bf16(afr[1][kt4 * 4 + kk2], b, acc[1][f], 0, 0, 0);
        }
      }
      __builtin_amdgcn_s_setprio(0);
      cur = cur + 1;
      if (cur >= 3) cur -= 3;
    }

    // per-tile epilogue: rowsum(exp) for strun rows + gated top-6 inserts.
    // Gate: if pack_val(max of 4) with the best-possible col field can't beat
    // the per-lane 6th key, no candidate can (exact: keys are unique).
#pragma unroll
    for (int i = 0; i < 4; ++i) {
      float s = 0.f;
#pragma unroll
      for (int f = 0; f < 4; ++f) s += __expf(2.0f * acc[1][f][i]);
      srow[i] += s;
#pragma unroll
      for (int g = 0; g < 2; ++g) {
        float m4 = fmaxf(fmaxf(acc[g][0][i], acc[g][1][i]), fmaxf(acc[g][2][i], acc[g][3][i]));
        unsigned gate = pack_val(m4) | 0x1FFFu;
        if (gate > p6[g][i][5]) {
#pragma unroll
          for (int f = 0; f < 4; ++f) {
            unsigned key = pack_key(acc[g][f][i], col0 + f * 16 + ml);
            if (key > p6[g][i][5]) {
#pragma unroll
              for (int j = 5; j >= 1; --j) {
                bool ap = key > p6[g][i][j - 1];
                unsigned keep = (key > p6[g][i][j]) ? key : p6[g][i][j];
                p6[g][i][j] = ap ? p6[g][i][j - 1] : keep;
              }
              if (key > p6[g][i][0]) p6[g][i][0] = key;
            }
          }
        }
      }
    }
  }

  // final: reduce rowsum + merge per-lane top-6 across the 16-lane group
#pragma unroll
  for (int i = 0; i < 4; ++i) {
    const int lrow = wave * 16 + q * 4 + i;
    {
      float s = srow[i];
      s += __shfl_xor(s, 1);
      s += __shfl_xor(s, 2);
      s += __shfl_xor(s, 4);
      s += __shfl_xor(s, 8);
      if (ml == 0) rowsum_part[(size_t)(row0 + lrow) * NPARTS + part] = s;
    }
#pragma unroll
    for (int g = 0; g < 2; ++g) {
      unsigned* dk = g ? keys_sm : keys_mm;
      const size_t o = ((size_t)(row0 + lrow) * NPARTS + part) * 6;
#pragma unroll
      for (int k = 0; k < 6; ++k) {
        unsigned mk = p6[g][i][0];
#pragma unroll
        for (int d = 1; d < 16; d <<= 1) {
          unsigned ok = (unsigned)__shfl_xor((int)mk, d);
          if (ok > mk) mk = ok;
        }
        if (ml == 0) dk[o + k] = mk;
        if (p6[g][i][0] == mk) {  // keys unique across lanes: pop my head
#pragma unroll
          for (int j = 0; j < 5; ++j) p6[g][i][j] = p6[g][i][j + 1];
          p6[g][i][5] = 0u;
        }
      }
    }
  }
}

// ---------------------------------------------------------------------------
// Merge per-part top-6 key lists (single unsigned compare does value-desc /
// idx-asc) + optional rowsum sum. Decodes col index from key low bits.
// ---------------------------------------------------------------------------
__global__ void merge_top6_kernel(const unsigned* __restrict__ part_keys,
                                  int* __restrict__ out_idx,
                                  const float* __restrict__ rowsum_part, float* __restrict__ rowsum,
                                  int do_rowsum) {
  int row = blockIdx.x * blockDim.x + threadIdx.x;
  if (row >= 8192) return;
  unsigned best[6] = {0u, 0u, 0u, 0u, 0u, 0u};
  for (int p = 0; p < NPARTS; ++p) {
#pragma unroll
    for (int c = 0; c < 6; ++c) {
      unsigned k = part_keys[((size_t)row * NPARTS + p) * 6 + c];
      if (k > best[5]) {
#pragma unroll
        for (int j = 5; j >= 1; --j) {
          bool ap = k > best[j - 1];
          unsigned keep = (k > best[j]) ? k : best[j];
          best[j] = ap ? best[j - 1] : keep;
        }
        if (k > best[0]) best[0] = k;
      }
    }
  }
#pragma unroll
  for (int j = 0; j < 6; ++j) out_idx[row * 6 + j] = 8191 - (int)(best[j] & 0x1FFFu);
  if (do_rowsum) {
    float s = 0.f;
    for (int p = 0; p < NPARTS; ++p) s += rowsum_part[(size_t)row * NPARTS + p];
    rowsum[row] = s;
  }
}

// ---------------------------------------------------------------------------
// Final loss: per row gather 6x6 neighbors, recompute 36 dots, -log(pos/rowsum)
// One wave per row.
// ---------------------------------------------------------------------------
__global__ void loss_kernel(const bf16* __restrict__ strun, const bf16* __restrict__ mmn,
                            const int* __restrict__ top6, const int* __restrict__ nbr,
                            const float* __restrict__ rowsum, float* __restrict__ out0) {
  int w = (int)((blockIdx.x * blockDim.x + threadIdx.x) >> 6);
  int lane = threadIdx.x & 63;
  if (w >= 8192) return;
  bf16x8 sv = *(const bf16x8*)(strun + (size_t)w * 512 + lane * 8);
  float sf[8];
#pragma unroll
  for (int e = 0; e < 8; ++e) sf[e] = (float)sv[e];
  float pos = 0.f;
  for (int k = 0; k < 6; ++k) {
    int j = top6[w * 6 + k];
#pragma unroll
    for (int l = 0; l < 6; ++l) {
      int m = nbr[j * 6 + l];
      bf16x8 mv = *(const bf16x8*)(mmn + (size_t)m * 512 + lane * 8);
      float d = 0.f;
#pragma unroll
      for (int e = 0; e < 8; ++e) d += sf[e] * (float)mv[e];
      d += __shfl_xor(d, 1);
      d += __shfl_xor(d, 2);
      d += __shfl_xor(d, 4);
      d += __shfl_xor(d, 8);
      d += __shfl_xor(d, 16);
      d += __shfl_xor(d, 32);
      pos += __expf(2.0f * d);
    }
  }
  if (lane == 0) {
    float loss_r = logf(rowsum[w]) - logf(pos);
    atomicAdd(out0, loss_r * (1.0f / 8192.0f));
  }
}

// ---------------------------------------------------------------------------
extern "C" void kernel_launch(void* const* d_in, const int* in_sizes, int n_in, void* d_out,
                              int out_size, void* d_ws, size_t ws_size, hipStream_t stream) {
  const float* stru = (const float*)d_in[0];
  const float* visu = (const float*)d_in[1];
  const float* ling = (const float*)d_in[2];
  const float* Wl1 = (const float*)d_in[3];
  const float* bl1 = (const float*)d_in[4];
  const float* Wl2 = (const float*)d_in[5];
  const float* bl2 = (const float*)d_in[6];
  const float* gl = (const float*)d_in[7];
  const float* betal = (const float*)d_in[8];
  const float* Wv1 = (const float*)d_in[9];
  const float* bv1 = (const float*)d_in[10];
  const float* Wv2 = (const float*)d_in[11];
  const float* bv2 = (const float*)d_in[12];
  const float* gv = (const float*)d_in[13];
  const float* betav = (const float*)d_in[14];
  float* out = (float*)d_out;

  char* p = (char*)d_ws;
  auto alloc = [&](size_t bytes) {
    char* r = p;
    p += (bytes + 255) & ~(size_t)255;
    return r;
  };
  bf16* strun = (bf16*)alloc((size_t)8192 * 512 * 2);
  bf16* W1t = (bf16*)alloc((size_t)512 * 4096 * 2);
  bf16* W2t = (bf16*)alloc((size_t)512 * 512 * 2);
  bf16* H1 = (bf16*)alloc((size_t)8192 * 512 * 2);
  float* H2 = (float*)alloc((size_t)8192 * 512 * 4);
  bf16* mmn = (bf16*)alloc((size_t)8192 * 512 * 2);
  float* colsum = (float*)alloc(512 * 4);
  float* colsumsq = (float*)alloc(512 * 4);
  float* rowsum_part = (float*)alloc((size_t)8192 * NPARTS * 4);
  float* rowsum = (float*)alloc((size_t)8192 * 4);
  unsigned* keys_mm = (unsigned*)alloc((size_t)8192 * NPARTS * 6 * 4);
  unsigned* keys_sm = (unsigned*)alloc((size_t)8192 * NPARTS * 6 * 4);
  int* nbr = (int*)alloc((size_t)8192 * 6 * 4);
  int* top6 = (int*)alloc((size_t)8192 * 6 * 4);

  // optional pre-cast buffer for MLP layer-1 A operand (guarded on ws_size)
  size_t xb_bytes = (size_t)8192 * 4096 * 2;
  size_t used = (size_t)(p - (char*)d_ws);
  bf16* Xb = nullptr;
  if (used + xb_bytes <= ws_size) Xb = (bf16*)alloc(xb_bytes);

  hipMemsetAsync(d_out, 0, 4, stream);
  row_normalize_kernel<<<8192, 256, 0, stream>>>(stru, strun);

  for (int br = 0; br < 2; ++br) {
    const float* X = (br == 0) ? ling : visu;
    int Kin = (br == 0) ? 768 : 4096;
    const float* W1 = (br == 0) ? Wl1 : Wv1;
    const float* b1 = (br == 0) ? bl1 : bv1;
    const float* W2 = (br == 0) ? Wl2 : Wv2;
    const float* b2 = (br == 0) ? bl2 : bv2;
    const float* g = (br == 0) ? gl : gv;
    const float* bet = (br == 0) ? betal : betav;
    float* mm_out = out + 1 + (size_t)br * 8192 * 512;

    transpose_cast_kernel<<<dim3(Kin / 64, 8), 256, 0, stream>>>(W1, W1t, Kin);
    transpose_cast_kernel<<<dim3(8, 8), 256, 0, stream>>>(W2, W2t, 512);

    if (Xb) {
      cast_bf16_kernel<<<2048, 256, 0, stream>>>(X, Xb, (long)8192 * Kin);
      gemm_nt_kernel<0, false><<<dim3(64, 8), 256, 0, stream>>>(
          Xb, W1t, b1, H1, nullptr, Kin);
    } else {
      gemm_nt_kernel<0, true><<<dim3(64, 8), 256, 0, stream>>>(
          X, W1t, b1, H1, nullptr, Kin);
    }
    gemm_nt_kernel<1, false><<<dim3(64, 8), 256, 0, stream>>>(
        H1, W2t, b2, nullptr, H2, 512);

    hipMemsetAsync(colsum, 0, 512 * 4, stream);
    hipMemsetAsync(colsumsq, 0, 512 * 4, stream);
    bn_stats_kernel<<<256, 512, 0, stream>>>(H2, colsum, colsumsq);
    bn_apply_kernel<<<8192, 512, 0, stream>>>(H2, colsum, colsumsq, g, bet, mm_out, mmn);

    // fused: nbr top-6 (mmn@mmn^T) + sm top-6 & rowsum (strun@mmn^T)
    topk_sm_fused_kernel<<<dim3(128, NPARTS), 256, 0, stream>>>(
        mmn, strun, mmn, keys_mm, keys_sm, rowsum_part);
    merge_top6_kernel<<<32, 256, 0, stream>>>(keys_mm, nbr, nullptr, nullptr, 0);
    merge_top6_kernel<<<32, 256, 0, stream>>>(keys_sm, top6, rowsum_part, rowsum, 1);

    loss_kernel<<<2048, 256, 0, stream>>>(strun, mmn, top6, nbr, rowsum, out);
  }
}

// Round 9
// 1059.164 us; speedup vs baseline: 1.0461x; 1.0461x over previous
//
#include <hip/hip_runtime.h>
#include <hip/hip_bf16.h>
#include <math.h>

typedef __bf16 bf16;
typedef __attribute__((ext_vector_type(8))) __bf16 bf16x8;
typedef __attribute__((ext_vector_type(4))) float floatx4;

static_assert(sizeof(bf16x8) == 16, "bf16x8 must be 16B");

// async global->LDS, 16B per lane. LDS dest is wave-uniform base + lane*16
// (HW rule, learn_hip m104); global src is per-lane.
__device__ __forceinline__ void gld16(bf16* lds, const bf16* g) {
  __builtin_amdgcn_global_load_lds((const __attribute__((address_space(1))) void*)g,
                                   (__attribute__((address_space(3))) void*)lds, 16, 0, 0);
}

// ---------------------------------------------------------------------------
// Row-normalize stru_feats (8192x512 fp32) -> bf16 unit rows
// ---------------------------------------------------------------------------
__global__ void row_normalize_kernel(const float* __restrict__ x, bf16* __restrict__ out) {
  __shared__ float red[256];
  int row = blockIdx.x;
  int t = threadIdx.x;
  float v0 = x[(size_t)row * 512 + t];
  float v1 = x[(size_t)row * 512 + t + 256];
  red[t] = v0 * v0 + v1 * v1;
  __syncthreads();
  for (int d = 128; d > 0; d >>= 1) {
    if (t < d) red[t] += red[t + d];
    __syncthreads();
  }
  float scale = 1.0f / (sqrtf(red[0]) + 1e-12f);
  out[(size_t)row * 512 + t] = (bf16)(v0 * scale);
  out[(size_t)row * 512 + t + 256] = (bf16)(v1 * scale);
}

// ---------------------------------------------------------------------------
// Elementwise fp32 -> bf16 cast (vectorized, grid-stride)
// ---------------------------------------------------------------------------
__global__ void cast_bf16_kernel(const float* __restrict__ x, bf16* __restrict__ out, long n) {
  long i = ((long)blockIdx.x * blockDim.x + threadIdx.x) * 8;
  long stride = (long)gridDim.x * blockDim.x * 8;
  for (; i < n; i += stride) {
    floatx4 a = *(const floatx4*)(x + i);
    floatx4 b = *(const floatx4*)(x + i + 4);
    bf16x8 v;
#pragma unroll
    for (int e = 0; e < 4; ++e) v[e] = (bf16)a[e];
#pragma unroll
    for (int e = 0; e < 4; ++e) v[e + 4] = (bf16)b[e];
    *(bf16x8*)(out + i) = v;
  }
}

// ---------------------------------------------------------------------------
// W [K][512] fp32 -> Wt [512][K] bf16, LDS-tiled so both sides are coalesced
// ---------------------------------------------------------------------------
__global__ void transpose_cast_kernel(const float* __restrict__ W, bf16* __restrict__ Wt, int K) {
  __shared__ float t[64][65];
  int k0 = blockIdx.x * 64;
  int n0 = blockIdx.y * 64;
#pragma unroll
  for (int m = 0; m < 16; ++m) {
    int kk = (threadIdx.x >> 6) + m * 4;
    int nn = threadIdx.x & 63;
    t[kk][nn] = W[(size_t)(k0 + kk) * 512 + n0 + nn];
  }
  __syncthreads();
#pragma unroll
  for (int m = 0; m < 16; ++m) {
    int nn = (threadIdx.x >> 6) + m * 4;
    int kk = threadIdx.x & 63;
    Wt[(size_t)(n0 + nn) * K + k0 + kk] = (bf16)t[kk][nn];
  }
}

// ---------------------------------------------------------------------------
// BN apply + write mm (fp32, to d_out) + row-normalized bf16 copy mmn
// ---------------------------------------------------------------------------
__global__ void bn_apply_kernel(const float* __restrict__ h, const float* __restrict__ colsum,
                                const float* __restrict__ colsumsq, const float* __restrict__ gamma,
                                const float* __restrict__ beta, float* __restrict__ mm_out,
                                bf16* __restrict__ mmn) {
  __shared__ float red[512];
  int row = blockIdx.x, col = threadIdx.x;  // 512 threads
  float mean = colsum[col] * (1.0f / 8192.0f);
  float var = colsumsq[col] * (1.0f / 8192.0f) - mean * mean;
  float inv = rsqrtf(var + 1e-5f);
  float y = (h[(size_t)row * 512 + col] - mean) * inv * gamma[col] + beta[col];
  mm_out[(size_t)row * 512 + col] = y;
  red[col] = y * y;
  __syncthreads();
  for (int d = 256; d > 0; d >>= 1) {
    if (col < d) red[col] += red[col + d];
    __syncthreads();
  }
  float scale = 1.0f / (sqrtf(red[0]) + 1e-12f);
  mmn[(size_t)row * 512 + col] = (bf16)(y * scale);
}

// ---------------------------------------------------------------------------
// MLP GEMM-NT via global_load_lds pipeline (R6 config — best measured):
// Block 128 rows x 64 cols; 4 waves, each wave 32 rows (2 groups) x 64 cols.
// Per K-step (BK=64): barrier (drains prev-step async loads) -> issue
// global_load_lds for step s+1 into the other buffer -> MFMA step s.
// Swizzle via pre-swizzled global source chunk (LDS dest linear, m173).
// MODE 0: +bias, leaky-relu, store bf16      (MLP layer 1)
// MODE 1: +bias, store fp32 + FUSED BN column stats (colsum/colsumsq
//         atomics; replaces the standalone bn_stats kernel)
// AF32 fallback (ws too small for pre-cast): simple 2-barrier staging.
// ---------------------------------------------------------------------------
template <int MODE, bool AF32>
__launch_bounds__(256, 2) __global__
void gemm_nt_kernel(const void* __restrict__ Av, const bf16* __restrict__ B,
                    const float* __restrict__ bias, bf16* __restrict__ out_bf,
                    float* __restrict__ out_f, float* __restrict__ colsum,
                    float* __restrict__ colsumsq, int K) {
  __shared__ __align__(16) bf16 As[2][128][64];
  __shared__ __align__(16) bf16 Bs[2][64][64];
  __shared__ float cs[4][64];
  __shared__ float cq[4][64];

  const int tid = threadIdx.x;
  const int lane = tid & 63;
  const int wave = tid >> 6;
  const int q = lane >> 4;
  const int ml = lane & 15;
  const int row0 = blockIdx.x * 128;
  const int col0 = blockIdx.y * 64;

  const float* Af = (const float*)Av;
  const bf16* Ab = (const bf16*)Av;

  floatx4 acc[2][4];
#pragma unroll
  for (int g = 0; g < 2; ++g)
#pragma unroll
    for (int f = 0; f < 4; ++f) acc[g][f] = (floatx4)0.0f;

  const int nsteps = K >> 6;

  if constexpr (!AF32) {
    // gld geometry: lane covers row-in-group (lane>>3), chunk (lane&7);
    // pre-swizzled global chunk = (lane&7) ^ (lane>>3)
    const int grow = lane >> 3;
    const int gch = (lane & 7) ^ grow;

    auto stageA = [&](int s, int b) {
      const int kt = s << 6;
#pragma unroll
      for (int m = 0; m < 4; ++m) {
        const int rb = m * 32 + wave * 8;  // rb % 8 == 0
        gld16(&As[b][rb][0], Ab + (size_t)(row0 + rb + grow) * K + kt + gch * 8);
      }
    };
    auto stageB = [&](int s, int b) {
      const int kt = s << 6;
#pragma unroll
      for (int m = 0; m < 2; ++m) {
        const int rb = m * 32 + wave * 8;
        gld16(&Bs[b][rb][0], B + (size_t)(col0 + rb + grow) * K + kt + gch * 8);
      }
    };

    stageA(0, 0);
    stageB(0, 0);
    for (int s = 0; s < nsteps; ++s) {
      const int b = s & 1;
      __syncthreads();  // vmcnt(0) drain: tile s complete; buffer b^1 free
      if (s + 1 < nsteps) {
        stageA(s + 1, b ^ 1);
        stageB(s + 1, b ^ 1);
      }
      __builtin_amdgcn_s_setprio(1);
#pragma unroll
      for (int kh = 0; kh < 2; ++kh) {
        const int slot = ((q + kh * 4) ^ (ml & 7)) * 8;
        bf16x8 a0 = *(const bf16x8*)&As[b][wave * 32 + ml][slot];
        bf16x8 a1 = *(const bf16x8*)&As[b][wave * 32 + 16 + ml][slot];
#pragma unroll
        for (int f = 0; f < 4; ++f) {
          bf16x8 bb = *(const bf16x8*)&Bs[b][f * 16 + ml][slot];
          acc[0][f] = __builtin_amdgcn_mfma_f32_16x16x32_bf16(a0, bb, acc[0][f], 0, 0, 0);
          acc[1][f] = __builtin_amdgcn_mfma_f32_16x16x32_bf16(a1, bb, acc[1][f], 0, 0, 0);
        }
      }
      __builtin_amdgcn_s_setprio(0);
    }
  } else {
    // fallback: fp32 A, cvt in regs, single buffer, 2 barriers/step
    const int sr = tid >> 3;
    const int sc = tid & 7;
    for (int s = 0; s < nsteps; ++s) {
      const int kt = s << 6;
      __syncthreads();
#pragma unroll
      for (int m = 0; m < 4; ++m) {
        int r = sr + m * 32;
        const float* pp = Af + (size_t)(row0 + r) * K + kt + sc * 8;
        bf16x8 v;
#pragma unroll
        for (int e = 0; e < 8; ++e) v[e] = (bf16)pp[e];
        *(bf16x8*)&As[0][r][(sc ^ (r & 7)) * 8] = v;
      }
#pragma unroll
      for (int m = 0; m < 2; ++m) {
        int r = sr + m * 32;
        *(bf16x8*)&Bs[0][r][(sc ^ (r & 7)) * 8] =
            *(const bf16x8*)(B + (size_t)(col0 + r) * K + kt + sc * 8);
      }
      __syncthreads();
#pragma unroll
      for (int kh = 0; kh < 2; ++kh) {
        const int slot = ((q + kh * 4) ^ (ml & 7)) * 8;
        bf16x8 a0 = *(const bf16x8*)&As[0][wave * 32 + ml][slot];
        bf16x8 a1 = *(const bf16x8*)&As[0][wave * 32 + 16 + ml][slot];
#pragma unroll
        for (int f = 0; f < 4; ++f) {
          bf16x8 bb = *(const bf16x8*)&Bs[0][f * 16 + ml][slot];
          acc[0][f] = __builtin_amdgcn_mfma_f32_16x16x32_bf16(a0, bb, acc[0][f], 0, 0, 0);
          acc[1][f] = __builtin_amdgcn_mfma_f32_16x16x32_bf16(a1, bb, acc[1][f], 0, 0, 0);
        }
      }
    }
  }

#pragma unroll
  for (int f = 0; f < 4; ++f) {
    int colg = col0 + f * 16 + ml;
    float bv = bias[colg];
    float s = 0.f, s2 = 0.f;
#pragma unroll
    for (int g = 0; g < 2; ++g)
#pragma unroll
      for (int i = 0; i < 4; ++i) {
        int rowg = row0 + wave * 32 + g * 16 + q * 4 + i;
        float v = acc[g][f][i] + bv;
        if constexpr (MODE == 0) {
          v = v >= 0.f ? v : 0.01f * v;
          out_bf[(size_t)rowg * 512 + colg] = (bf16)v;
        } else {
          out_f[(size_t)rowg * 512 + colg] = v;
          s += v;
          s2 += v * v;
        }
      }
    if constexpr (MODE == 1) {
      // fused BN stats: reduce the 8 rows/lane over the 4 q-groups (lanes
      // differing only in bits 4-5), then per-wave LDS slice.
      s += __shfl_xor(s, 16);
      s += __shfl_xor(s, 32);
      s2 += __shfl_xor(s2, 16);
      s2 += __shfl_xor(s2, 32);
      if (q == 0) {
        cs[wave][f * 16 + ml] = s;
        cq[wave][f * 16 + ml] = s2;
      }
    }
  }
  if constexpr (MODE == 1) {
    __syncthreads();
    if (tid < 64) {
      atomicAdd(&colsum[col0 + tid], cs[0][tid] + cs[1][tid] + cs[2][tid] + cs[3][tid]);
      atomicAdd(&colsumsq[col0 + tid], cq[0][tid] + cq[1][tid] + cq[2][tid] + cq[3][tid]);
    }
  }
}

// ---------------------------------------------------------------------------
// FUSED top-k / softmax-sum GEMM-NT, global_load_lds pipeline (R6 config —
// best measured: 215 us, 0 bank conflicts).
// Computes BOTH  mmn @ mmn^T (neighbor top-6)  and  strun @ mmn^T (sm top-6 +
// rowsum(exp(2c)))  in one pass over the shared B tile (mmn).
// Block: 64 rows (of BOTH A matrices) x 1024 cols (16 tiles of 64), K=512.
// Phase t (64 phases): barrier (drains tile-t async loads) -> issue
// global_load_lds tile t+1 into Bs[(t+1)&1] -> MFMA tile t.
// Swizzle via pre-swizzled global source: LDS[r][c] = global chunk c^(r&15).
// Top-6 per-lane as packed keys: (monotonic_bits(v) & ~0x1FFF) | (8191-col).
// ---------------------------------------------------------------------------
__device__ __forceinline__ unsigned pack_key(float v, int col) {
  unsigned u = __float_as_uint(v);
  u = (u & 0x80000000u) ? ~u : (u | 0x80000000u);
  return (u & 0xFFFFE000u) | (unsigned)(8191 - col);
}

#define NPARTS 8

__launch_bounds__(256, 2) __global__
void topk_sm_fused_kernel(const bf16* __restrict__ Amm, const bf16* __restrict__ Ast,
                          const bf16* __restrict__ B, unsigned* __restrict__ keys_mm,
                          unsigned* __restrict__ keys_sm, float* __restrict__ rowsum_part) {
  __shared__ __align__(16) bf16 Bs[2][64][128];

  const int tid = threadIdx.x;
  const int lane = tid & 63;
  const int wave = tid >> 6;
  const int q = lane >> 4;
  const int ml = lane & 15;
  const int row0 = blockIdx.x * 64;
  const int part = blockIdx.y;

  // gld geometry: lane covers row-in-group (lane>>4), chunk (lane&15);
  // row&15 for this lane = wave*4 + (lane>>4); pre-swizzled global chunk:
  const int strw = wave * 4 + (lane >> 4);
  const int gch = (lane & 15) ^ strw;

  // A fragments resident in registers: g=0 -> mmn rows, g=1 -> strun rows
  bf16x8 afr[2][16];
#pragma unroll
  for (int g = 0; g < 2; ++g) {
    const bf16* ap = (g == 0 ? Amm : Ast) + (size_t)(row0 + wave * 16 + ml) * 512 + q * 8;
#pragma unroll
    for (int s = 0; s < 16; ++s) afr[g][s] = *(const bf16x8*)(ap + s * 32);
  }

  // per-lane packed top-6 for the 4 rows (q*4+i) of each A-set
  unsigned p6[2][4][6];
#pragma unroll
  for (int g = 0; g < 2; ++g)
#pragma unroll
    for (int i = 0; i < 4; ++i)
#pragma unroll
      for (int j = 0; j < 6; ++j) p6[g][i][j] = 0u;
  float srow[4] = {0.f, 0.f, 0.f, 0.f};

  // stage tile u (u = ct*4 + ktile) into buffer b, async, zero registers
  auto stage = [&](int u, int b) {
    const bf16* bp =
        B + (size_t)(part * 1024 + (u >> 2) * 64 + strw) * 512 + (u & 3) * 128 + gch * 8;
#pragma unroll
    for (int m = 0; m < 4; ++m)
      gld16(&Bs[b][wave * 4 + m * 16][0], bp + (size_t)m * 16 * 512);
  };

  // prologue: issue tile 0
  stage(0, 0);

  for (int ct = 0; ct < 16; ++ct) {
    const int col0 = part * 1024 + ct * 64;
    floatx4 acc[2][4];
#pragma unroll
    for (int g = 0; g < 2; ++g)
#pragma unroll
      for (int f = 0; f < 4; ++f) acc[g][f] = (floatx4)0.0f;

#pragma unroll
    for (int kt4 = 0; kt4 < 4; ++kt4) {
      const int t = ct * 4 + kt4;
      __syncthreads();  // vmcnt(0) drain: tile t complete in Bs[t&1]; Bs[^1] free
      if (t < 63) stage(t + 1, (t + 1) & 1);  // async, covered by MFMA phase
      __builtin_amdgcn_s_setprio(1);
#pragma unroll
      for (int kk2 = 0; kk2 < 4; ++kk2) {
#pragma unroll
        for (int f = 0; f < 4; ++f) {
          const int sc2 = (kk2 * 4 + q) ^ ml;
          bf16x8 b = *(const bf16x8*)&Bs[t & 1][f * 16 + ml][sc2 * 8];
          acc[0][f] = __builtin_amdgcn_mfma_f32_16x16x32_bf16(afr[0][kt4 * 4 + kk2], b, acc[0][f], 0, 0, 0);
          acc[1][f] = __builtin_amdgcn_mfma_f32_16x16x32_bf16(afr[1][kt4 * 4 + kk2], b, acc[1][f], 0, 0, 0);
        }
      }
      __builtin_amdgcn_s_setprio(0);
    }

    // per-tile epilogue: rowsum(exp) for strun rows + packed top-6 inserts
    // (overlaps with the in-flight async loads of the next ct's first tile)
#pragma unroll
    for (int i = 0; i < 4; ++i) {
      float s = 0.f;
#pragma unroll
      for (int f = 0; f < 4; ++f) s += __expf(2.0f * acc[1][f][i]);
      srow[i] += s;
#pragma unroll
      for (int g = 0; g < 2; ++g)
#pragma unroll
        for (int f = 0; f < 4; ++f) {
          unsigned key = pack_key(acc[g][f][i], col0 + f * 16 + ml);
          if (key > p6[g][i][5]) {
#pragma unroll
            for (int j = 5; j >= 1; --j) {
              bool ap = key > p6[g][i][j - 1];
              unsigned keep = (key > p6[g][i][j]) ? key : p6[g][i][j];
              p6[g][i][j] = ap ? p6[g][i][j - 1] : keep;
            }
            if (key > p6[g][i][0]) p6[g][i][0] = key;
          }
        }
    }
  }

  // final: reduce rowsum + merge per-lane top-6 across the 16-lane group
#pragma unroll
  for (int i = 0; i < 4; ++i) {
    const int lrow = wave * 16 + q * 4 + i;
    {
      float s = srow[i];
      s += __shfl_xor(s, 1);
      s += __shfl_xor(s, 2);
      s += __shfl_xor(s, 4);
      s += __shfl_xor(s, 8);
      if (ml == 0) rowsum_part[(size_t)(row0 + lrow) * NPARTS + part] = s;
    }
#pragma unroll
    for (int g = 0; g < 2; ++g) {
      unsigned* dk = g ? keys_sm : keys_mm;
      const size_t o = ((size_t)(row0 + lrow) * NPARTS + part) * 6;
#pragma unroll
      for (int k = 0; k < 6; ++k) {
        unsigned mk = p6[g][i][0];
#pragma unroll
        for (int d = 1; d < 16; d <<= 1) {
          unsigned ok = (unsigned)__shfl_xor((int)mk, d);
          if (ok > mk) mk = ok;
        }
        if (ml == 0) dk[o + k] = mk;
        if (p6[g][i][0] == mk) {  // keys unique across lanes: pop my head
#pragma unroll
          for (int j = 0; j < 5; ++j) p6[g][i][j] = p6[g][i][j + 1];
          p6[g][i][5] = 0u;
        }
      }
    }
  }
}

// ---------------------------------------------------------------------------
// DUAL merge: per row, merge both per-part top-6 key lists (mm -> nbr,
// sm -> top6) + rowsum sum. One launch replaces two.
// ---------------------------------------------------------------------------
__device__ __forceinline__ void merge6(const unsigned* __restrict__ keys, int row,
                                       int* __restrict__ out_idx) {
  unsigned best[6] = {0u, 0u, 0u, 0u, 0u, 0u};
  for (int p = 0; p < NPARTS; ++p) {
#pragma unroll
    for (int c = 0; c < 6; ++c) {
      unsigned k = keys[((size_t)row * NPARTS + p) * 6 + c];
      if (k > best[5]) {
#pragma unroll
        for (int j = 5; j >= 1; --j) {
          bool ap = k > best[j - 1];
          unsigned keep = (k > best[j]) ? k : best[j];
          best[j] = ap ? best[j - 1] : keep;
        }
        if (k > best[0]) best[0] = k;
      }
    }
  }
#pragma unroll
  for (int j = 0; j < 6; ++j) out_idx[row * 6 + j] = 8191 - (int)(best[j] & 0x1FFFu);
}

__global__ void merge_top6_dual_kernel(const unsigned* __restrict__ keys_mm,
                                       const unsigned* __restrict__ keys_sm,
                                       int* __restrict__ nbr, int* __restrict__ top6,
                                       const float* __restrict__ rowsum_part,
                                       float* __restrict__ rowsum) {
  int row = blockIdx.x * blockDim.x + threadIdx.x;
  if (row >= 8192) return;
  merge6(keys_mm, row, nbr);
  merge6(keys_sm, row, top6);
  float s = 0.f;
  for (int p = 0; p < NPARTS; ++p) s += rowsum_part[(size_t)row * NPARTS + p];
  rowsum[row] = s;
}

// ---------------------------------------------------------------------------
// Final loss: per row gather 6x6 neighbors, recompute 36 dots, -log(pos/rowsum)
// One wave per row.
// ---------------------------------------------------------------------------
__global__ void loss_kernel(const bf16* __restrict__ strun, const bf16* __restrict__ mmn,
                            const int* __restrict__ top6, const int* __restrict__ nbr,
                            const float* __restrict__ rowsum, float* __restrict__ out0) {
  int w = (int)((blockIdx.x * blockDim.x + threadIdx.x) >> 6);
  int lane = threadIdx.x & 63;
  if (w >= 8192) return;
  bf16x8 sv = *(const bf16x8*)(strun + (size_t)w * 512 + lane * 8);
  float sf[8];
#pragma unroll
  for (int e = 0; e < 8; ++e) sf[e] = (float)sv[e];
  float pos = 0.f;
  for (int k = 0; k < 6; ++k) {
    int j = top6[w * 6 + k];
#pragma unroll
    for (int l = 0; l < 6; ++l) {
      int m = nbr[j * 6 + l];
      bf16x8 mv = *(const bf16x8*)(mmn + (size_t)m * 512 + lane * 8);
      float d = 0.f;
#pragma unroll
      for (int e = 0; e < 8; ++e) d += sf[e] * (float)mv[e];
      d += __shfl_xor(d, 1);
      d += __shfl_xor(d, 2);
      d += __shfl_xor(d, 4);
      d += __shfl_xor(d, 8);
      d += __shfl_xor(d, 16);
      d += __shfl_xor(d, 32);
      pos += __expf(2.0f * d);
    }
  }
  if (lane == 0) {
    float loss_r = logf(rowsum[w]) - logf(pos);
    atomicAdd(out0, loss_r * (1.0f / 8192.0f));
  }
}

// ---------------------------------------------------------------------------
extern "C" void kernel_launch(void* const* d_in, const int* in_sizes, int n_in, void* d_out,
                              int out_size, void* d_ws, size_t ws_size, hipStream_t stream) {
  const float* stru = (const float*)d_in[0];
  const float* visu = (const float*)d_in[1];
  const float* ling = (const float*)d_in[2];
  const float* Wl1 = (const float*)d_in[3];
  const float* bl1 = (const float*)d_in[4];
  const float* Wl2 = (const float*)d_in[5];
  const float* bl2 = (const float*)d_in[6];
  const float* gl = (const float*)d_in[7];
  const float* betal = (const float*)d_in[8];
  const float* Wv1 = (const float*)d_in[9];
  const float* bv1 = (const float*)d_in[10];
  const float* Wv2 = (const float*)d_in[11];
  const float* bv2 = (const float*)d_in[12];
  const float* gv = (const float*)d_in[13];
  const float* betav = (const float*)d_in[14];
  float* out = (float*)d_out;

  char* p = (char*)d_ws;
  auto alloc = [&](size_t bytes) {
    char* r = p;
    p += (bytes + 255) & ~(size_t)255;
    return r;
  };
  bf16* strun = (bf16*)alloc((size_t)8192 * 512 * 2);
  bf16* W1t = (bf16*)alloc((size_t)512 * 4096 * 2);
  bf16* W2t = (bf16*)alloc((size_t)512 * 512 * 2);
  bf16* H1 = (bf16*)alloc((size_t)8192 * 512 * 2);
  float* H2 = (float*)alloc((size_t)8192 * 512 * 4);
  bf16* mmn = (bf16*)alloc((size_t)8192 * 512 * 2);
  float* colsum = (float*)alloc(512 * 4);
  float* colsumsq = (float*)alloc(512 * 4);
  float* rowsum_part = (float*)alloc((size_t)8192 * NPARTS * 4);
  float* rowsum = (float*)alloc((size_t)8192 * 4);
  unsigned* keys_mm = (unsigned*)alloc((size_t)8192 * NPARTS * 6 * 4);
  unsigned* keys_sm = (unsigned*)alloc((size_t)8192 * NPARTS * 6 * 4);
  int* nbr = (int*)alloc((size_t)8192 * 6 * 4);
  int* top6 = (int*)alloc((size_t)8192 * 6 * 4);

  // optional pre-cast buffer for MLP layer-1 A operand (guarded on ws_size)
  size_t xb_bytes = (size_t)8192 * 4096 * 2;
  size_t used = (size_t)(p - (char*)d_ws);
  bf16* Xb = nullptr;
  if (used + xb_bytes <= ws_size) Xb = (bf16*)alloc(xb_bytes);

  hipMemsetAsync(d_out, 0, 4, stream);
  row_normalize_kernel<<<8192, 256, 0, stream>>>(stru, strun);

  for (int br = 0; br < 2; ++br) {
    const float* X = (br == 0) ? ling : visu;
    int Kin = (br == 0) ? 768 : 4096;
    const float* W1 = (br == 0) ? Wl1 : Wv1;
    const float* b1 = (br == 0) ? bl1 : bv1;
    const float* W2 = (br == 0) ? Wl2 : Wv2;
    const float* b2 = (br == 0) ? bl2 : bv2;
    const float* g = (br == 0) ? gl : gv;
    const float* bet = (br == 0) ? betal : betav;
    float* mm_out = out + 1 + (size_t)br * 8192 * 512;

    transpose_cast_kernel<<<dim3(Kin / 64, 8), 256, 0, stream>>>(W1, W1t, Kin);
    transpose_cast_kernel<<<dim3(8, 8), 256, 0, stream>>>(W2, W2t, 512);

    if (Xb) {
      cast_bf16_kernel<<<2048, 256, 0, stream>>>(X, Xb, (long)8192 * Kin);
      gemm_nt_kernel<0, false><<<dim3(64, 8), 256, 0, stream>>>(
          Xb, W1t, b1, H1, nullptr, nullptr, nullptr, Kin);
    } else {
      gemm_nt_kernel<0, true><<<dim3(64, 8), 256, 0, stream>>>(
          X, W1t, b1, H1, nullptr, nullptr, nullptr, Kin);
    }

    // L2 GEMM with fused BN column stats (bn_stats kernel eliminated)
    hipMemsetAsync(colsum, 0, 512 * 4, stream);
    hipMemsetAsync(colsumsq, 0, 512 * 4, stream);
    gemm_nt_kernel<1, false><<<dim3(64, 8), 256, 0, stream>>>(
        H1, W2t, b2, nullptr, H2, colsum, colsumsq, 512);

    bn_apply_kernel<<<8192, 512, 0, stream>>>(H2, colsum, colsumsq, g, bet, mm_out, mmn);

    // fused: nbr top-6 (mmn@mmn^T) + sm top-6 & rowsum (strun@mmn^T)
    topk_sm_fused_kernel<<<dim3(128, NPARTS), 256, 0, stream>>>(
        mmn, strun, mmn, keys_mm, keys_sm, rowsum_part);
    merge_top6_dual_kernel<<<32, 256, 0, stream>>>(keys_mm, keys_sm, nbr, top6, rowsum_part,
                                                   rowsum);

    loss_kernel<<<2048, 256, 0, stream>>>(strun, mmn, top6, nbr, rowsum, out);
  }
}